// Round 14
// baseline (325.476 us; speedup 1.0000x reference)
//
#include <hip/hip_runtime.h>
#include <hip/hip_cooperative_groups.h>

namespace cg = cooperative_groups;

#define HDIM 256
#define NREL 16
#define NBLK 128
#define AWPB 8    // waves per agg block (each wave = 2 nodes)
#define PBLK 256  // preprocess blocks (1 per CU)
#define PTHR 512  // preprocess threads per block

typedef __attribute__((ext_vector_type(8))) _Float16 f16x8;
typedef __attribute__((ext_vector_type(2))) _Float16 h2;
typedef __attribute__((ext_vector_type(4))) float f32x4;

__device__ __forceinline__ unsigned short f2h(float f) {
    return __builtin_bit_cast(unsigned short, (_Float16)f);
}
__device__ __forceinline__ float h2f(unsigned short s) {
    return (float)__builtin_bit_cast(_Float16, s);
}

// ---------------- cooperative fused preprocess ----------------
// phase0: x->fp16, loop_w -> fp16 transposed, zero deg
// phase1: dst histogram
// phase2: two-level exclusive scan -> start/cnt (start[M] = E)
// phase3: scatter edges into dst-sorted epack
__global__ __launch_bounds__(PTHR) void pre_kernel(
    const float* __restrict__ x, unsigned short* __restrict__ xh,
    const float* __restrict__ lw1, unsigned short* __restrict__ w1t,
    const float* __restrict__ lw2, unsigned short* __restrict__ w2t,
    const int* __restrict__ src, const int* __restrict__ dst,
    const int* __restrict__ et, const float* __restrict__ norm,
    int* __restrict__ deg, int* __restrict__ start, int* __restrict__ cnt,
    int2* __restrict__ epack, int* __restrict__ blockSum,
    int nx, int M, int E)
{
    cg::grid_group grid = cg::this_grid();
    const int gtid = blockIdx.x * blockDim.x + threadIdx.x;
    const int gstride = gridDim.x * blockDim.x;

    // ---- phase 0 ----
    const int total0 = nx + 131072 + M;
    for (int i = gtid; i < total0; i += gstride) {
        if (i < nx) {
            xh[i] = f2h(x[i]);
        } else if (i < nx + 65536) {
            int j = i - nx; int n = j >> 8, k = j & 255;
            w1t[j] = f2h(lw1[k * HDIM + n]);   // W^T[n][k]
        } else if (i < nx + 131072) {
            int j = i - nx - 65536; int n = j >> 8, k = j & 255;
            w2t[j] = f2h(lw2[k * HDIM + n]);
        } else {
            deg[i - nx - 131072] = 0;
        }
    }
    grid.sync();

    // ---- phase 1: histogram ----
    for (int e = gtid; e < E; e += gstride)
        atomicAdd(&deg[dst[e]], 1);
    grid.sync();

    // ---- phase 2a: per-block bin sums (bin = gtid; PBLK*PTHR = 131072 >= M) ----
    __shared__ int sh[PTHR];
    const int bin = gtid;
    const int dv = (bin < M) ? deg[bin] : 0;
    sh[threadIdx.x] = dv;
    __syncthreads();
    for (int ofs = PTHR / 2; ofs > 0; ofs >>= 1) {
        if (threadIdx.x < ofs) sh[threadIdx.x] += sh[threadIdx.x + ofs];
        __syncthreads();
    }
    if (threadIdx.x == 0) blockSum[blockIdx.x] = sh[0];
    grid.sync();

    // ---- phase 2b: block 0 scans the PBLK block sums (exclusive) ----
    if (blockIdx.x == 0) {
        const int v = (threadIdx.x < PBLK) ? blockSum[threadIdx.x] : 0;
        sh[threadIdx.x] = v;
        __syncthreads();
        for (int ofs = 1; ofs < PTHR; ofs <<= 1) {
            const int t = (threadIdx.x >= ofs) ? sh[threadIdx.x - ofs] : 0;
            __syncthreads();
            sh[threadIdx.x] += t;
            __syncthreads();
        }
        if (threadIdx.x < PBLK) blockSum[threadIdx.x] = sh[threadIdx.x] - v;  // exclusive
        if (threadIdx.x == PBLK - 1) start[M] = sh[threadIdx.x];              // total = E
    }
    grid.sync();

    // ---- phase 2c: block-local exclusive scan + global offset ----
    sh[threadIdx.x] = dv;
    __syncthreads();
    for (int ofs = 1; ofs < PTHR; ofs <<= 1) {
        const int t = (threadIdx.x >= ofs) ? sh[threadIdx.x - ofs] : 0;
        __syncthreads();
        sh[threadIdx.x] += t;
        __syncthreads();
    }
    if (bin < M) {
        const int s0 = blockSum[blockIdx.x] + sh[threadIdx.x] - dv;  // exclusive
        start[bin] = s0;
        cnt[bin] = s0;
    }
    grid.sync();

    // ---- phase 3: scatter ----
    for (int e = gtid; e < E; e += gstride) {
        const int d = dst[e];
        const int pos = atomicAdd(&cnt[d], 1);
        epack[pos] = make_int2(src[e] * NREL + et[e], __float_as_int(norm[e]));
    }
}

// ---------------- per-edge micro-matmul: lane owns blocks b0..b0+3 (8 channels) ----------------
__device__ __forceinline__ void accum8(float acc[8], uint4 xa, uint4 w0, uint4 w1, h2 nm2) {
    h2 xs0 = __builtin_bit_cast(h2, xa.x) * nm2;
    h2 xs1 = __builtin_bit_cast(h2, xa.y) * nm2;
    h2 xs2 = __builtin_bit_cast(h2, xa.z) * nm2;
    h2 xs3 = __builtin_bit_cast(h2, xa.w) * nm2;
    acc[0] = __builtin_amdgcn_fdot2(xs0, __builtin_bit_cast(h2, w0.x), acc[0], false);
    acc[1] = __builtin_amdgcn_fdot2(xs0, __builtin_bit_cast(h2, w1.x), acc[1], false);
    acc[2] = __builtin_amdgcn_fdot2(xs1, __builtin_bit_cast(h2, w0.y), acc[2], false);
    acc[3] = __builtin_amdgcn_fdot2(xs1, __builtin_bit_cast(h2, w1.y), acc[3], false);
    acc[4] = __builtin_amdgcn_fdot2(xs2, __builtin_bit_cast(h2, w0.z), acc[4], false);
    acc[5] = __builtin_amdgcn_fdot2(xs2, __builtin_bit_cast(h2, w1.z), acc[5], false);
    acc[6] = __builtin_amdgcn_fdot2(xs3, __builtin_bit_cast(h2, w0.w), acc[6], false);
    acc[7] = __builtin_amdgcn_fdot2(xs3, __builtin_bit_cast(h2, w1.w), acc[7], false);
}

// process 2 edges (one per half-wave): int4 q = (e_even, n_even, e_odd, n_odd)
__device__ __forceinline__ void edge2(float acc[8], const unsigned short* __restrict__ xin,
                                      const unsigned int* wp, int4 q, int hl, int c2, int b0) {
    const int   e  = hl ? q.z : q.x;
    const float nm = __int_as_float(hl ? q.w : q.y);
    const _Float16 nh = (_Float16)nm;
    const h2 nm2 = {nh, nh};
    const uint4 xa = *(const uint4*)(xin + (size_t)(e >> 4) * HDIM + c2);
    const int r = e & (NREL - 1);
    const uint4 w0 = *(const uint4*)(wp + (r * 2 + 0) * NBLK + b0);
    const uint4 w1 = *(const uint4*)(wp + (r * 2 + 1) * NBLK + b0);
    accum8(acc, xa, w0, w1, nm2);
}

// ---------------- pull aggregation (round-9 verbatim): 2 nodes/wave, fp16 out ----------------
__global__ __launch_bounds__(512, 4) void agg_kernel(
    const unsigned short* __restrict__ xin,  // fp16 [M,256]
    const int2* __restrict__ epack,
    const int* __restrict__ start,
    const float* __restrict__ w,             // (R,B,2,2) f32
    unsigned short* __restrict__ aggH,       // fp16 [M,256] out
    int N)
{
    __shared__ unsigned int wp[NREL * 2 * NBLK];   // 16 KB packed fp16 weight pairs
    for (int j = threadIdx.x; j < NREL * 256; j += blockDim.x) {
        int r = j >> 8, t8 = j & 255, b = t8 >> 1, io = t8 & 1;
        float w0 = w[r * 512 + b * 4 + io];
        float w1 = w[r * 512 + b * 4 + 2 + io];
        wp[(r * 2 + io) * NBLK + b] = (unsigned)f2h(w0) | ((unsigned)f2h(w1) << 16);
    }
    __syncthreads();

    const int wv  = threadIdx.x >> 6;
    const int l   = threadIdx.x & 63;
    const int hl  = l >> 5;
    const int m32 = l & 31;
    const int c2  = m32 * 8;
    const int b0  = m32 * 4;

    const int pair = blockIdx.x * AWPB + wv;
    const int dA = pair * 2;
    if (dA >= N) return;
    const int dB = dA + 1;
    const bool hasB = (dB < N);

    int iA = start[dA];
    const int eA = start[dA + 1];
    int iB = hasB ? start[dB] : 0;
    const int eB = hasB ? start[dB + 1] : 0;

    float accA[8] = {0.f,0.f,0.f,0.f,0.f,0.f,0.f,0.f};
    float accB[8] = {0.f,0.f,0.f,0.f,0.f,0.f,0.f,0.f};

    while (iA + 4 <= eA && iB + 4 <= eB) {
        const int4 qA0 = *(const int4*)&epack[iA + 0];
        const int4 qA1 = *(const int4*)&epack[iA + 2];
        const int4 qB0 = *(const int4*)&epack[iB + 0];
        const int4 qB1 = *(const int4*)&epack[iB + 2];
        edge2(accA, xin, wp, qA0, hl, c2, b0);
        edge2(accB, xin, wp, qB0, hl, c2, b0);
        edge2(accA, xin, wp, qA1, hl, c2, b0);
        edge2(accB, xin, wp, qB1, hl, c2, b0);
        iA += 4; iB += 4;
    }
    for (; iA + 8 <= eA; iA += 8) {
        const int4 q0 = *(const int4*)&epack[iA + 0];
        const int4 q1 = *(const int4*)&epack[iA + 2];
        const int4 q2 = *(const int4*)&epack[iA + 4];
        const int4 q3 = *(const int4*)&epack[iA + 6];
        edge2(accA, xin, wp, q0, hl, c2, b0);
        edge2(accA, xin, wp, q1, hl, c2, b0);
        edge2(accA, xin, wp, q2, hl, c2, b0);
        edge2(accA, xin, wp, q3, hl, c2, b0);
    }
    for (; iA + 2 <= eA; iA += 2) {
        const int4 q = *(const int4*)&epack[iA];
        edge2(accA, xin, wp, q, hl, c2, b0);
    }
    if (iA < eA) {
        const int2 p = epack[iA];
        edge2(accA, xin, wp, make_int4(p.x, p.y, p.x, 0), hl, c2, b0);
    }
    for (; iB + 8 <= eB; iB += 8) {
        const int4 q0 = *(const int4*)&epack[iB + 0];
        const int4 q1 = *(const int4*)&epack[iB + 2];
        const int4 q2 = *(const int4*)&epack[iB + 4];
        const int4 q3 = *(const int4*)&epack[iB + 6];
        edge2(accB, xin, wp, q0, hl, c2, b0);
        edge2(accB, xin, wp, q1, hl, c2, b0);
        edge2(accB, xin, wp, q2, hl, c2, b0);
        edge2(accB, xin, wp, q3, hl, c2, b0);
    }
    for (; iB + 2 <= eB; iB += 2) {
        const int4 q = *(const int4*)&epack[iB];
        edge2(accB, xin, wp, q, hl, c2, b0);
    }
    if (iB < eB) {
        const int2 p = epack[iB];
        edge2(accB, xin, wp, make_int4(p.x, p.y, p.x, 0), hl, c2, b0);
    }

    #pragma unroll
    for (int k = 0; k < 8; ++k) {
        accA[k] += __shfl_xor(accA[k], 32);
        accB[k] += __shfl_xor(accB[k], 32);
    }
    const int o = 4 * hl;
    ushort4 sA;
    sA.x = f2h(accA[o + 0]); sA.y = f2h(accA[o + 1]);
    sA.z = f2h(accA[o + 2]); sA.w = f2h(accA[o + 3]);
    *(ushort4*)(aggH + (size_t)dA * HDIM + c2 + o) = sA;
    if (hasB) {
        ushort4 sB;
        sB.x = f2h(accB[o + 0]); sB.y = f2h(accB[o + 1]);
        sB.z = f2h(accB[o + 2]); sB.w = f2h(accB[o + 3]);
        *(ushort4*)(aggH + (size_t)dB * HDIM + c2 + o) = sB;
    }
}

// ---------------- MFMA self-loop GEMM (round-9 verbatim): out = [relu](A @ W^T + bias + aggH) ----------------
template <int RELU_H>
__global__ __launch_bounds__(256) void mfma_gemm(
    const unsigned short* __restrict__ A,     // [M,256] fp16
    const unsigned short* __restrict__ BT,    // [256,256] fp16, BT[n][k] = W[k][n]
    const float* __restrict__ bias,
    const unsigned short* aggH,               // fp16 agg (may alias hb)
    float* __restrict__ outF,
    unsigned short* hb,
    int M)
{
    const int wv = threadIdx.x >> 6;
    const int l  = threadIdx.x & 63;
    const int lr = l & 15;
    const int lk = l >> 4;
    const int mblk = blockIdx.x * 32;
    const int n0 = wv * 64;

    f32x4 acc[2][4] = {};

    const unsigned short* arow0 = A + (size_t)(mblk + lr) * HDIM + lk * 8;
    const unsigned short* arow1 = arow0 + 16 * HDIM;
    const unsigned short* brow0 = BT + (size_t)(n0 + lr) * HDIM + lk * 8;

    #pragma unroll
    for (int ks = 0; ks < 8; ++ks) {
        const int k0 = ks * 32;
        const f16x8 a0 = *(const f16x8*)(arow0 + k0);
        const f16x8 a1 = *(const f16x8*)(arow1 + k0);
        #pragma unroll
        for (int j = 0; j < 4; ++j) {
            const f16x8 b = *(const f16x8*)(brow0 + j * 16 * HDIM + k0);
            acc[0][j] = __builtin_amdgcn_mfma_f32_16x16x32_f16(a0, b, acc[0][j], 0, 0, 0);
            acc[1][j] = __builtin_amdgcn_mfma_f32_16x16x32_f16(a1, b, acc[1][j], 0, 0, 0);
        }
    }

    #pragma unroll
    for (int i = 0; i < 2; ++i) {
        #pragma unroll
        for (int j = 0; j < 4; ++j) {
            const int gn = n0 + 16 * j + lr;
            const float bv = bias[gn];
            #pragma unroll
            for (int q = 0; q < 4; ++q) {
                const int gm = mblk + 16 * i + lk * 4 + q;
                if (gm < M) {
                    float v = acc[i][j][q] + bv + h2f(aggH[(size_t)gm * HDIM + gn]);
                    if (RELU_H) {
                        hb[(size_t)gm * HDIM + gn] = f2h(fmaxf(v, 0.f));
                    } else {
                        outF[(size_t)gm * HDIM + gn] = v;
                    }
                }
            }
        }
    }
}

extern "C" void kernel_launch(void* const* d_in, const int* in_sizes, int n_in,
                              void* d_out, int out_size, void* d_ws, size_t ws_size,
                              hipStream_t stream) {
    const float* x    = (const float*)d_in[0];
    const int*   src  = (const int*)d_in[1];
    const int*   dst  = (const int*)d_in[2];
    const int*   et   = (const int*)d_in[3];
    const float* norm = (const float*)d_in[4];
    const float* w1   = (const float*)d_in[5];
    const float* lw1  = (const float*)d_in[6];
    const float* b1   = (const float*)d_in[7];
    const float* w2   = (const float*)d_in[8];
    const float* lw2  = (const float*)d_in[9];
    const float* b2   = (const float*)d_in[10];

    const int M = in_sizes[0] / HDIM;   // 20000
    const int E = in_sizes[1];          // 320000

    float* out = (float*)d_out;
    char*  ws  = (char*)d_ws;

    // ws layout (~23.2 MB)
    size_t off = 0;
    unsigned short* xh   = (unsigned short*)(ws + off); off += (size_t)M * HDIM * 2;
    unsigned short* hbuf = (unsigned short*)(ws + off); off += (size_t)M * HDIM * 2;
    unsigned short* w1t  = (unsigned short*)(ws + off); off += 65536 * 2;
    unsigned short* w2t  = (unsigned short*)(ws + off); off += 65536 * 2;
    int* start = (int*)(ws + off);  off += (size_t)(M + 1) * 4; off = (off + 15) & ~15ull;
    int* cnt   = (int*)(ws + off);  off += (size_t)M * 4;       off = (off + 15) & ~15ull;
    int* deg   = (int*)(ws + off);  off += (size_t)M * 4;       off = (off + 15) & ~15ull;
    int* bsum  = (int*)(ws + off);  off += (size_t)PBLK * 4;    off = (off + 15) & ~15ull;
    int2* epack = (int2*)(ws + off); off += (size_t)E * 8;
    (void)ws_size;

    // ---- fused cooperative preprocess (1 dispatch replaces 4) ----
    {
        int nx = M * HDIM;
        int Mv = M, Ev = E;
        void* args[] = {
            (void*)&x, (void*)&xh, (void*)&lw1, (void*)&w1t, (void*)&lw2, (void*)&w2t,
            (void*)&src, (void*)&dst, (void*)&et, (void*)&norm,
            (void*)&deg, (void*)&start, (void*)&cnt, (void*)&epack, (void*)&bsum,
            (void*)&nx, (void*)&Mv, (void*)&Ev
        };
        hipLaunchCooperativeKernel((const void*)pre_kernel, dim3(PBLK), dim3(PTHR),
                                   args, 0, stream);
    }

    const int npair = (M + 1) / 2;
    const int nblk  = (npair + AWPB - 1) / AWPB;
    const int gblk  = (M + 31) / 32;

    // Layer 1: agg1 -> hbuf (fp16); gemm1: hbuf <- fp16(relu(aggH + b1 + xh@lw1)) in place
    agg_kernel<<<nblk, 512, 0, stream>>>(xh, epack, start, w1, hbuf, M);
    mfma_gemm<1><<<gblk, 256, 0, stream>>>(xh, w1t, b1, hbuf, nullptr, hbuf, M);

    // Layer 2: agg2 -> xh-space (dead); gemm2: out = agg2 + b2 + hbuf@lw2
    agg_kernel<<<nblk, 512, 0, stream>>>(hbuf, epack, start, w2, xh, M);
    mfma_gemm<0><<<gblk, 256, 0, stream>>>(hbuf, w2t, b2, xh, out, nullptr, M);
}

// Round 15
// 204.238 us; speedup vs baseline: 1.5936x; 1.5936x over previous
//
#include <hip/hip_runtime.h>

#define HDIM 256
#define NREL 16
#define NBLK 128
#define AWPB 8   // waves per agg block (each wave = 2 nodes)

typedef __attribute__((ext_vector_type(8))) _Float16 f16x8;
typedef __attribute__((ext_vector_type(2))) _Float16 h2;
typedef __attribute__((ext_vector_type(4))) float f32x4;

__device__ __forceinline__ unsigned short f2h(float f) {
    return __builtin_bit_cast(unsigned short, (_Float16)f);
}
__device__ __forceinline__ float h2f(unsigned short s) {
    return (float)__builtin_bit_cast(_Float16, s);
}

// ---------------- convert x->fp16, loop_w -> fp16 transposed, zero deg ----------------
__global__ void convert_kernel(const float* __restrict__ x, unsigned short* __restrict__ xh,
                               const float* __restrict__ lw1, unsigned short* __restrict__ w1t,
                               const float* __restrict__ lw2, unsigned short* __restrict__ w2t,
                               int* __restrict__ deg, int nx, int M) {
    const int total = nx + 131072 + M;
    for (int i = blockIdx.x * blockDim.x + threadIdx.x; i < total; i += gridDim.x * blockDim.x) {
        if (i < nx) {
            xh[i] = f2h(x[i]);
        } else if (i < nx + 65536) {
            int j = i - nx; int n = j >> 8, k = j & 255;
            w1t[j] = f2h(lw1[k * HDIM + n]);   // W^T[n][k]
        } else if (i < nx + 131072) {
            int j = i - nx - 65536; int n = j >> 8, k = j & 255;
            w2t[j] = f2h(lw2[k * HDIM + n]);
        } else {
            deg[i - nx - 131072] = 0;
        }
    }
}

// ---------------- counting-sort by dst ----------------
__global__ void hist_kernel(const int* __restrict__ dst, int* __restrict__ deg, int E) {
    for (int e = blockIdx.x * blockDim.x + threadIdx.x; e < E; e += gridDim.x * blockDim.x)
        atomicAdd(&deg[dst[e]], 1);
}

__global__ __launch_bounds__(1024) void scan_kernel(const int* __restrict__ deg,
                                                    int* __restrict__ start,
                                                    int* __restrict__ cnt, int N) {
    __shared__ int part[1024];
    const int t = threadIdx.x;
    const int CH = (N + 1023) >> 10;
    const int c0 = t * CH;
    int sum = 0;
    for (int i = 0; i < CH; ++i) { int idx = c0 + i; if (idx < N) sum += deg[idx]; }
    part[t] = sum;
    __syncthreads();
    for (int off = 1; off < 1024; off <<= 1) {
        int v = (t >= off) ? part[t - off] : 0;
        __syncthreads();
        part[t] += v;
        __syncthreads();
    }
    int run = (t > 0) ? part[t - 1] : 0;
    for (int i = 0; i < CH; ++i) {
        int idx = c0 + i;
        if (idx < N) { start[idx] = run; cnt[idx] = run; run += deg[idx]; }
    }
    if (t == 1023) start[N] = part[1023];
}

__global__ void scatter_kernel(const int* __restrict__ src, const int* __restrict__ dst,
                               const int* __restrict__ et, const float* __restrict__ norm,
                               int* __restrict__ cnt, int2* __restrict__ epack, int E) {
    for (int e = blockIdx.x * blockDim.x + threadIdx.x; e < E; e += gridDim.x * blockDim.x) {
        int d = dst[e];
        int pos = atomicAdd(&cnt[d], 1);
        epack[pos] = make_int2(src[e] * NREL + et[e], __float_as_int(norm[e]));
    }
}

// ---------------- per-edge micro-matmul: lane owns blocks b0..b0+3 (8 channels) ----------------
__device__ __forceinline__ void accum8(float acc[8], uint4 xa, uint4 w0, uint4 w1, h2 nm2) {
    h2 xs0 = __builtin_bit_cast(h2, xa.x) * nm2;
    h2 xs1 = __builtin_bit_cast(h2, xa.y) * nm2;
    h2 xs2 = __builtin_bit_cast(h2, xa.z) * nm2;
    h2 xs3 = __builtin_bit_cast(h2, xa.w) * nm2;
    acc[0] = __builtin_amdgcn_fdot2(xs0, __builtin_bit_cast(h2, w0.x), acc[0], false);
    acc[1] = __builtin_amdgcn_fdot2(xs0, __builtin_bit_cast(h2, w1.x), acc[1], false);
    acc[2] = __builtin_amdgcn_fdot2(xs1, __builtin_bit_cast(h2, w0.y), acc[2], false);
    acc[3] = __builtin_amdgcn_fdot2(xs1, __builtin_bit_cast(h2, w1.y), acc[3], false);
    acc[4] = __builtin_amdgcn_fdot2(xs2, __builtin_bit_cast(h2, w0.z), acc[4], false);
    acc[5] = __builtin_amdgcn_fdot2(xs2, __builtin_bit_cast(h2, w1.z), acc[5], false);
    acc[6] = __builtin_amdgcn_fdot2(xs3, __builtin_bit_cast(h2, w0.w), acc[6], false);
    acc[7] = __builtin_amdgcn_fdot2(xs3, __builtin_bit_cast(h2, w1.w), acc[7], false);
}

// process 2 edges (one per half-wave): int4 q = (e_even, n_even, e_odd, n_odd)
__device__ __forceinline__ void edge2(float acc[8], const unsigned short* __restrict__ xin,
                                      const unsigned int* wp, int4 q, int hl, int c2, int b0) {
    const int   e  = hl ? q.z : q.x;
    const float nm = __int_as_float(hl ? q.w : q.y);
    const _Float16 nh = (_Float16)nm;
    const h2 nm2 = {nh, nh};
    const uint4 xa = *(const uint4*)(xin + (size_t)(e >> 4) * HDIM + c2);
    const int r = e & (NREL - 1);
    const uint4 w0 = *(const uint4*)(wp + (r * 2 + 0) * NBLK + b0);
    const uint4 w1 = *(const uint4*)(wp + (r * 2 + 1) * NBLK + b0);
    accum8(acc, xa, w0, w1, nm2);
}

// ---------------- pull aggregation: 2 nodes per wave, interleaved streams, fp16 out ----------------
__global__ __launch_bounds__(512, 4) void agg_kernel(
    const unsigned short* __restrict__ xin,  // fp16 [M,256]
    const int2* __restrict__ epack,
    const int* __restrict__ start,
    const float* __restrict__ w,             // (R,B,2,2) f32
    unsigned short* __restrict__ aggH,       // fp16 [M,256] out
    int N)
{
    __shared__ unsigned int wp[NREL * 2 * NBLK];   // 16 KB packed fp16 weight pairs
    for (int j = threadIdx.x; j < NREL * 256; j += blockDim.x) {
        int r = j >> 8, t8 = j & 255, b = t8 >> 1, io = t8 & 1;
        float w0 = w[r * 512 + b * 4 + io];
        float w1 = w[r * 512 + b * 4 + 2 + io];
        wp[(r * 2 + io) * NBLK + b] = (unsigned)f2h(w0) | ((unsigned)f2h(w1) << 16);
    }
    __syncthreads();

    const int wv  = threadIdx.x >> 6;
    const int l   = threadIdx.x & 63;
    const int hl  = l >> 5;
    const int m32 = l & 31;
    const int c2  = m32 * 8;
    const int b0  = m32 * 4;

    const int pair = blockIdx.x * AWPB + wv;
    const int dA = pair * 2;
    if (dA >= N) return;
    const int dB = dA + 1;
    const bool hasB = (dB < N);

    int iA = start[dA];
    const int eA = start[dA + 1];
    int iB = hasB ? start[dB] : 0;
    const int eB = hasB ? start[dB + 1] : 0;

    float accA[8] = {0.f,0.f,0.f,0.f,0.f,0.f,0.f,0.f};
    float accB[8] = {0.f,0.f,0.f,0.f,0.f,0.f,0.f,0.f};

    // interleaved main loop: 4 edges of A + 4 of B per iter
    while (iA + 4 <= eA && iB + 4 <= eB) {
        const int4 qA0 = *(const int4*)&epack[iA + 0];
        const int4 qA1 = *(const int4*)&epack[iA + 2];
        const int4 qB0 = *(const int4*)&epack[iB + 0];
        const int4 qB1 = *(const int4*)&epack[iB + 2];
        edge2(accA, xin, wp, qA0, hl, c2, b0);
        edge2(accB, xin, wp, qB0, hl, c2, b0);
        edge2(accA, xin, wp, qA1, hl, c2, b0);
        edge2(accB, xin, wp, qB1, hl, c2, b0);
        iA += 4; iB += 4;
    }
    // drain A
    for (; iA + 8 <= eA; iA += 8) {
        const int4 q0 = *(const int4*)&epack[iA + 0];
        const int4 q1 = *(const int4*)&epack[iA + 2];
        const int4 q2 = *(const int4*)&epack[iA + 4];
        const int4 q3 = *(const int4*)&epack[iA + 6];
        edge2(accA, xin, wp, q0, hl, c2, b0);
        edge2(accA, xin, wp, q1, hl, c2, b0);
        edge2(accA, xin, wp, q2, hl, c2, b0);
        edge2(accA, xin, wp, q3, hl, c2, b0);
    }
    for (; iA + 2 <= eA; iA += 2) {
        const int4 q = *(const int4*)&epack[iA];
        edge2(accA, xin, wp, q, hl, c2, b0);
    }
    if (iA < eA) {
        const int2 p = epack[iA];
        edge2(accA, xin, wp, make_int4(p.x, p.y, p.x, 0), hl, c2, b0);
    }
    // drain B
    for (; iB + 8 <= eB; iB += 8) {
        const int4 q0 = *(const int4*)&epack[iB + 0];
        const int4 q1 = *(const int4*)&epack[iB + 2];
        const int4 q2 = *(const int4*)&epack[iB + 4];
        const int4 q3 = *(const int4*)&epack[iB + 6];
        edge2(accB, xin, wp, q0, hl, c2, b0);
        edge2(accB, xin, wp, q1, hl, c2, b0);
        edge2(accB, xin, wp, q2, hl, c2, b0);
        edge2(accB, xin, wp, q3, hl, c2, b0);
    }
    for (; iB + 2 <= eB; iB += 2) {
        const int4 q = *(const int4*)&epack[iB];
        edge2(accB, xin, wp, q, hl, c2, b0);
    }
    if (iB < eB) {
        const int2 p = epack[iB];
        edge2(accB, xin, wp, make_int4(p.x, p.y, p.x, 0), hl, c2, b0);
    }

    #pragma unroll
    for (int k = 0; k < 8; ++k) {
        accA[k] += __shfl_xor(accA[k], 32);
        accB[k] += __shfl_xor(accB[k], 32);
    }
    const int o = 4 * hl;
    ushort4 sA;
    sA.x = f2h(accA[o + 0]); sA.y = f2h(accA[o + 1]);
    sA.z = f2h(accA[o + 2]); sA.w = f2h(accA[o + 3]);
    *(ushort4*)(aggH + (size_t)dA * HDIM + c2 + o) = sA;
    if (hasB) {
        ushort4 sB;
        sB.x = f2h(accB[o + 0]); sB.y = f2h(accB[o + 1]);
        sB.z = f2h(accB[o + 2]); sB.w = f2h(accB[o + 3]);
        *(ushort4*)(aggH + (size_t)dB * HDIM + c2 + o) = sB;
    }
}

// ---------------- MFMA self-loop GEMM: out = [relu](A @ W^T + bias + aggH) ----------------
// Block = 256 thr = 4 waves; 32 m-rows x 256 n-cols (wave wv: n0 = 64*wv).
// RELU_H=1: hb[gm][gn] = fp16(relu(v)); hb MAY equal aggH (same-thread same-slot
//           read-before-write, element-wise — safe). RELU_H=0: outF[gm][gn] = v.
template <int RELU_H>
__global__ __launch_bounds__(256) void mfma_gemm(
    const unsigned short* __restrict__ A,     // [M,256] fp16
    const unsigned short* __restrict__ BT,    // [256,256] fp16, BT[n][k] = W[k][n]
    const float* __restrict__ bias,
    const unsigned short* aggH,               // fp16 agg (no restrict: may alias hb)
    float* __restrict__ outF,
    unsigned short* hb,
    int M)
{
    const int wv = threadIdx.x >> 6;
    const int l  = threadIdx.x & 63;
    const int lr = l & 15;
    const int lk = l >> 4;
    const int mblk = blockIdx.x * 32;
    const int n0 = wv * 64;

    f32x4 acc[2][4] = {};

    const unsigned short* arow0 = A + (size_t)(mblk + lr) * HDIM + lk * 8;
    const unsigned short* arow1 = arow0 + 16 * HDIM;
    const unsigned short* brow0 = BT + (size_t)(n0 + lr) * HDIM + lk * 8;

    #pragma unroll
    for (int ks = 0; ks < 8; ++ks) {
        const int k0 = ks * 32;
        const f16x8 a0 = *(const f16x8*)(arow0 + k0);
        const f16x8 a1 = *(const f16x8*)(arow1 + k0);
        #pragma unroll
        for (int j = 0; j < 4; ++j) {
            const f16x8 b = *(const f16x8*)(brow0 + j * 16 * HDIM + k0);
            acc[0][j] = __builtin_amdgcn_mfma_f32_16x16x32_f16(a0, b, acc[0][j], 0, 0, 0);
            acc[1][j] = __builtin_amdgcn_mfma_f32_16x16x32_f16(a1, b, acc[1][j], 0, 0, 0);
        }
    }

    #pragma unroll
    for (int i = 0; i < 2; ++i) {
        #pragma unroll
        for (int j = 0; j < 4; ++j) {
            const int gn = n0 + 16 * j + lr;
            const float bv = bias[gn];
            #pragma unroll
            for (int q = 0; q < 4; ++q) {
                const int gm = mblk + 16 * i + lk * 4 + q;
                if (gm < M) {
                    float v = acc[i][j][q] + bv + h2f(aggH[(size_t)gm * HDIM + gn]);
                    if (RELU_H) {
                        hb[(size_t)gm * HDIM + gn] = f2h(fmaxf(v, 0.f));
                    } else {
                        outF[(size_t)gm * HDIM + gn] = v;
                    }
                }
            }
        }
    }
}

extern "C" void kernel_launch(void* const* d_in, const int* in_sizes, int n_in,
                              void* d_out, int out_size, void* d_ws, size_t ws_size,
                              hipStream_t stream) {
    const float* x    = (const float*)d_in[0];
    const int*   src  = (const int*)d_in[1];
    const int*   dst  = (const int*)d_in[2];
    const int*   et   = (const int*)d_in[3];
    const float* norm = (const float*)d_in[4];
    const float* w1   = (const float*)d_in[5];
    const float* lw1  = (const float*)d_in[6];
    const float* b1   = (const float*)d_in[7];
    const float* w2   = (const float*)d_in[8];
    const float* lw2  = (const float*)d_in[9];
    const float* b2   = (const float*)d_in[10];

    const int M = in_sizes[0] / HDIM;   // 20000
    const int E = in_sizes[1];          // 320000

    float* out = (float*)d_out;
    char*  ws  = (char*)d_ws;

    // ws layout (~23.2 MB). Buffer lifetimes:
    //   xh: layer-1 features; dead after gemm1 -> reused as aggH(L2) by agg2.
    //   hbuf: aggH(L1) written by agg1; gemm1 reads aggH elem + writes h fp16 to SAME slot.
    size_t off = 0;
    unsigned short* xh   = (unsigned short*)(ws + off); off += (size_t)M * HDIM * 2;
    unsigned short* hbuf = (unsigned short*)(ws + off); off += (size_t)M * HDIM * 2;
    unsigned short* w1t  = (unsigned short*)(ws + off); off += 65536 * 2;
    unsigned short* w2t  = (unsigned short*)(ws + off); off += 65536 * 2;
    int* start = (int*)(ws + off);  off += (size_t)(M + 1) * 4; off = (off + 15) & ~15ull;
    int* cnt   = (int*)(ws + off);  off += (size_t)M * 4;       off = (off + 15) & ~15ull;
    int* deg   = (int*)(ws + off);  off += (size_t)M * 4;       off = (off + 15) & ~15ull;
    int2* epack = (int2*)(ws + off); off += (size_t)E * 8;
    (void)ws_size;

    // ---- preprocess ----
    convert_kernel<<<2048, 256, 0, stream>>>(x, xh, lw1, w1t, lw2, w2t, deg, M * HDIM, M);
    hist_kernel<<<512, 256, 0, stream>>>(dst, deg, E);
    scan_kernel<<<1, 1024, 0, stream>>>(deg, start, cnt, M);
    scatter_kernel<<<512, 256, 0, stream>>>(src, dst, et, norm, cnt, epack, E);

    const int npair = (M + 1) / 2;
    const int nblk  = (npair + AWPB - 1) / AWPB;
    const int gblk  = (M + 31) / 32;

    // Layer 1: agg1 -> hbuf (fp16); gemm1: hbuf <- fp16(relu(aggH + b1 + xh@lw1)) in place
    agg_kernel<<<nblk, 512, 0, stream>>>(xh, epack, start, w1, hbuf, M);
    mfma_gemm<1><<<gblk, 256, 0, stream>>>(xh, w1t, b1, hbuf, nullptr, hbuf, M);

    // Layer 2: agg2 -> xh-space (dead); gemm2: out = agg2 + b2 + hbuf@lw2
    agg_kernel<<<nblk, 512, 0, stream>>>(hbuf, epack, start, w2, xh, M);
    mfma_gemm<0><<<gblk, 256, 0, stream>>>(hbuf, w2t, b2, xh, out, nullptr, M);
}